// Round 12
// baseline (218.249 us; speedup 1.0000x reference)
//
#include <hip/hip_runtime.h>
#include <hip/hip_bf16.h>
#include <cstdint>
#include <cstddef>

typedef __bf16 bf16x8 __attribute__((ext_vector_type(8)));
typedef _Float16 f16x8 __attribute__((ext_vector_type(8)));
typedef short short8 __attribute__((ext_vector_type(8)));
typedef short short4v __attribute__((ext_vector_type(4)));
typedef float f32x4 __attribute__((ext_vector_type(4)));

// Device pass: use the gfx950 K=16 bf16 MFMA (HW-verified working, rounds 8-10).
// Host pass: builtins are undeclared -> inert stand-in (host only parses, never
// executes device bodies). Round-11 failed because the host pass saw a bogus
// builtin name in the #else branch.
#if defined(__HIP_DEVICE_COMPILE__)
  #define MFMA16BF(a,b,c) __builtin_amdgcn_mfma_f32_16x16x16bf16_1k((a),(b),(c),0,0,0)
  #define MFMA32F16(a,b,c) __builtin_amdgcn_mfma_f32_16x16x32_f16((a),(b),(c),0,0,0)
  #define MFMA32BF(a,b,c)  __builtin_amdgcn_mfma_f32_16x16x32_bf16((a),(b),(c),0,0,0)
#else
  #define MFMA16BF(a,b,c)  (c)
  #define MFMA32F16(a,b,c) (c)
  #define MFMA32BF(a,b,c)  (c)
#endif

#if defined(__HIP_DEVICE_COMPILE__) && __has_builtin(__builtin_amdgcn_exp2f)
  #define EXP2F(x) __builtin_amdgcn_exp2f(x)
#else
  #define EXP2F(x) exp2f(x)
#endif

__device__ __forceinline__ unsigned short f2bf(float f) {
    union { float f; uint32_t u; } v; v.f = f;
    uint32_t u = v.u;
    return (unsigned short)((u + 0x7FFFu + ((u >> 16) & 1u)) >> 16);
}
__device__ __forceinline__ float bf2f(unsigned short h) {
    union { uint32_t u; float f; } v; v.u = ((uint32_t)h) << 16;
    return v.f;
}
__device__ __forceinline__ unsigned short f2h(float f) {
    union { _Float16 h; unsigned short u; } v; v.h = (_Float16)f;
    return v.u;
}

// ---------------------------------------------------------------------------
// Kernel 0: preconvert weights (unchanged).
// ---------------------------------------------------------------------------
__global__ __launch_bounds__(256) void prep_kernel(
    const float* __restrict__ Wq, const float* __restrict__ Wk,
    const float* __restrict__ Wv, const float* __restrict__ Wo,
    const float* __restrict__ wg,
    unsigned short* __restrict__ wt_hi,
    unsigned short* __restrict__ wt_lo,
    unsigned short* __restrict__ wot,
    float* __restrict__ gamma)
{
    const int bid = blockIdx.x, t = threadIdx.x;
    __shared__ __align__(16) unsigned short Th[128][72], Tl[128][72];
    if (bid < 12) {
        const int proj = bid >> 2, kc = bid & 3;
        const float* W = (proj == 0) ? Wq : ((proj == 1) ? Wk : Wv);
        for (int r = 0; r < 32; ++r) {
            int idx = r * 256 + t;
            int kk = idx >> 7, n = idx & 127;
            float w = W[(size_t)(kc * 64 + kk) * 128 + n];
            unsigned short h = f2bf(w);
            Th[n][kk] = h;
            Tl[n][kk] = f2bf(w - bf2f(h));
        }
        __syncthreads();
        int n = t >> 1, k0 = (t & 1) * 32;
        size_t off = (size_t)proj * 32768 + (size_t)kc * 8192 + (size_t)n * 64 + k0;
        #pragma unroll
        for (int j = 0; j < 4; ++j) {
            *(short8*)(wt_hi + off + j * 8) = *(const short8*)(&Th[n][k0 + j * 8]);
            *(short8*)(wt_lo + off + j * 8) = *(const short8*)(&Tl[n][k0 + j * 8]);
        }
    } else if (bid < 16) {
        const int c0 = (bid - 12) * 64;
        unsigned short* T = &Th[0][0];
        for (int r = 0; r < 32; ++r) {
            int idx = r * 256 + t;
            int a = idx >> 6, cc = idx & 63;
            T[cc * 136 + a] = f2bf(Wo[(size_t)a * 256 + c0 + cc]);
        }
        __syncthreads();
        int cc = t >> 2, a0 = (t & 3) * 32;
        #pragma unroll
        for (int j = 0; j < 4; ++j)
            *(short8*)(wot + (size_t)(c0 + cc) * 128 + a0 + j * 8) =
                *(const short8*)(&T[cc * 136 + a0 + j * 8]);
    } else {
        float g = 1.0f + wg[t];
        if (g < 0.f) g = 0.f;
        gamma[t] = tanhf(g);
    }
}

// ---------------------------------------------------------------------------
// Kernel 1: q/k/v projections. q,k fp16 row-major.
// v stored in PV-fragment layout: Vp[b][s>>2][d][s&3] (b64-coalesced stores
// in the epilogue AND b64-coalesced fragment loads in attn).
// grid (256 row-tiles, 3 proj), block 256.
// ---------------------------------------------------------------------------
__global__ __launch_bounds__(256) void qkv_kernel(
    const float* __restrict__ x,
    const unsigned short* __restrict__ wt_hi,
    const unsigned short* __restrict__ wt_lo,
    unsigned short* __restrict__ qkv_ws)
{
    const int rowtile = blockIdx.x;
    const int proj    = blockIdx.y;
    unsigned short* outqk = qkv_ws + (size_t)proj * 2097152u;
    unsigned short* vp    = qkv_ws + (size_t)2 * 2097152u;
    const bool need_lo = (proj < 2);

    const int tid  = threadIdx.x;
    const int lane = tid & 63, wave = tid >> 6;
    const int lo   = lane & 15, quad = lane >> 4;

    __shared__ __align__(16) unsigned short Xh[64][72], Xl[64][72];
    __shared__ __align__(16) unsigned short Wh[128][72], Wl[128][72];

    f32x4 acc[8];
    #pragma unroll
    for (int i = 0; i < 8; ++i) acc[i] = (f32x4){0.f, 0.f, 0.f, 0.f};

    const int wn = tid >> 1, wk0 = (tid & 1) * 32;

    for (int kc = 0; kc < 4; ++kc) {
        __syncthreads();
        #pragma unroll
        for (int i = 0; i < 4; ++i) {
            int flat4 = (i * 256 + tid) * 4;
            int row = flat4 >> 6, col = flat4 & 63;
            float4 tv4 = *(const float4*)(x + (size_t)(rowtile * 64 + row) * 256 + kc * 64 + col);
            float tv[4] = {tv4.x, tv4.y, tv4.z, tv4.w};
            short4v h, l;
            #pragma unroll
            for (int j = 0; j < 4; ++j) {
                unsigned short hj = f2bf(tv[j]);
                h[j] = (short)hj;
                l[j] = (short)f2bf(tv[j] - bf2f(hj));
            }
            *(short4v*)(&Xh[row][col]) = h;
            if (need_lo) *(short4v*)(&Xl[row][col]) = l;
        }
        {
            const size_t off = (size_t)proj * 32768 + (size_t)kc * 8192 + (size_t)wn * 64 + wk0;
            #pragma unroll
            for (int j = 0; j < 4; ++j)
                *(short8*)(&Wh[wn][wk0 + j * 8]) = *(const short8*)(wt_hi + off + j * 8);
            if (need_lo) {
                #pragma unroll
                for (int j = 0; j < 4; ++j)
                    *(short8*)(&Wl[wn][wk0 + j * 8]) = *(const short8*)(wt_lo + off + j * 8);
            }
        }
        __syncthreads();
        #pragma unroll
        for (int ks = 0; ks < 2; ++ks) {
            bf16x8 ah = *(const bf16x8*)(&Xh[wave * 16 + lo][ks * 32 + quad * 8]);
            #pragma unroll
            for (int nb = 0; nb < 8; ++nb) {
                bf16x8 bh = *(const bf16x8*)(&Wh[nb * 16 + lo][ks * 32 + quad * 8]);
                acc[nb] = MFMA32BF(ah, bh, acc[nb]);
                if (need_lo) {
                    bf16x8 al = *(const bf16x8*)(&Xl[wave * 16 + lo][ks * 32 + quad * 8]);
                    bf16x8 bl = *(const bf16x8*)(&Wl[nb * 16 + lo][ks * 32 + quad * 8]);
                    acc[nb] = MFMA32BF(al, bh, acc[nb]);
                    acc[nb] = MFMA32BF(ah, bl, acc[nb]);
                }
            }
        }
    }
    if (proj < 2) {
        #pragma unroll
        for (int nb = 0; nb < 8; ++nb) {
            #pragma unroll
            for (int r = 0; r < 4; ++r) {
                float v = acc[nb][r];
                v = (v >= 0.f) ? v : 0.2f * v;
                int m = rowtile * 64 + wave * 16 + quad * 4 + r;
                outqk[(size_t)m * 128 + nb * 16 + lo] = f2h(v);
            }
        }
    } else {
        // Vp[b][sc][d][j]: sc = seq>>2, j = seq&3.  seq = sb + wave*16 + quad*4 + r
        // -> sc = (sb>>2) + wave*4 + quad, j = r.  One b64 store per nb.
        const int b  = rowtile >> 6;
        const int sc = ((rowtile & 63) << 4) + wave * 4 + quad;
        unsigned short* vpb = vp + (size_t)b * 524288u + (size_t)sc * 512u;
        #pragma unroll
        for (int nb = 0; nb < 8; ++nb) {
            short4v o4;
            #pragma unroll
            for (int r = 0; r < 4; ++r) {
                float v = acc[nb][r];
                v = (v >= 0.f) ? v : 0.2f * v;
                o4[r] = (short)f2bf(v);
            }
            *(short4v*)(vpb + (size_t)(nb * 16 + lo) * 4) = o4;
        }
    }
}

// ---------------------------------------------------------------------------
// Kernel 2: flash attention — NO LDS, NO BARRIERS.  K fragments loaded
// directly from global (row-major fp16 k: each frag load = 16 fully-used 64B
// lines, L1-cached across the block's 4 waves); V fragments loaded directly
// from the Vp layout (coalesced b64).  P in registers (S^T C-layout ==
// 16x16x16 A-layout).  grid (4, 32, nsplit), block 256.
// ---------------------------------------------------------------------------
__global__ __launch_bounds__(256) void attn_kernel(
    const unsigned short* __restrict__ qkv_ws,
    unsigned short* __restrict__ part,   // [nsplit][16384][128] bf16
    float* __restrict__ lpart,           // [nsplit][16384] fp32
    int chunk)
{
    const int b  = blockIdx.x;
    const int qt = blockIdx.y;
    const int z  = blockIdx.z;
    const int tid  = threadIdx.x;
    const int lane = tid & 63, wave = tid >> 6;
    const int lo   = lane & 15, quad = lane >> 4;

    const unsigned short* q  = qkv_ws;
    const unsigned short* k  = qkv_ws + 2097152u;
    const unsigned short* vp = qkv_ws + (size_t)2 * 2097152u + (size_t)b * 524288u;

    const int qbase = qt * 128 + wave * 32;
    f16x8 qf[2][4];
    #pragma unroll
    for (int g = 0; g < 2; ++g)
        #pragma unroll
        for (int ks = 0; ks < 4; ++ks)
            qf[g][ks] = *(const f16x8*)(q + ((size_t)(b * 4096 + qbase + g * 16 + lo)) * 128
                                          + ks * 32 + quad * 8);

    f32x4 oacc[2][8];
    #pragma unroll
    for (int g = 0; g < 2; ++g)
        #pragma unroll
        for (int i = 0; i < 8; ++i) oacc[g][i] = (f32x4){0.f, 0.f, 0.f, 0.f};
    float Lsum[2] = {1e-30f, 1e-30f};

    const float LOG2E  = 1.44269504088896f;
    const float NSHIFT = -40.0f * 1.44269504088896f;

    const int niter = chunk >> 5;
    const int sbase = z * chunk;

    // K-frag base: row = b*4096 + sbase + s0 + st*16 + lo, col = ks*32 + quad*8
    const unsigned short* kbase = k + ((size_t)(b * 4096 + sbase + lo)) * 128 + quad * 8;

    for (int kt = 0; kt < niter; ++kt) {
        const int s0 = kt * 32;

        // QK(t): S^T = K·Q^T. K frags direct from global (L1/L2).
        f32x4 sT[2][2];
        sT[0][0] = (f32x4){0.f,0.f,0.f,0.f}; sT[0][1] = (f32x4){0.f,0.f,0.f,0.f};
        sT[1][0] = (f32x4){0.f,0.f,0.f,0.f}; sT[1][1] = (f32x4){0.f,0.f,0.f,0.f};
        #pragma unroll
        for (int st = 0; st < 2; ++st) {
            const unsigned short* krow = kbase + (size_t)(s0 + st * 16) * 128;
            #pragma unroll
            for (int ks = 0; ks < 4; ++ks) {
                f16x8 kf = *(const f16x8*)(krow + ks * 32);
                sT[0][st] = MFMA32F16(kf, qf[0][ks], sT[0][st]);
                sT[1][st] = MFMA32F16(kf, qf[1][ks], sT[1][st]);
            }
        }
        // V frags issued now; the exp block below covers their L2 latency.
        short4v vf[2][8];
        #pragma unroll
        for (int st = 0; st < 2; ++st) {
            const int sc = ((sbase + s0 + st * 16) >> 2) + quad;
            const unsigned short* vrow = vp + (size_t)sc * 512u + (size_t)lo * 4;
            #pragma unroll
            for (int nb = 0; nb < 8; ++nb)
                vf[st][nb] = *(const short4v*)(vrow + nb * 64);
        }
        // P = exp(s-40), bf16-truncated in registers (A-frag: k = quad*4 + j).
        short4v Pp[2][2];
        #pragma unroll
        for (int g = 0; g < 2; ++g) {
            #pragma unroll
            for (int st = 0; st < 2; ++st) {
                #pragma unroll
                for (int r = 0; r < 4; ++r) {
                    float t = fminf(fmaf(sT[g][st][r], LOG2E, NSHIFT), 125.0f);
                    union { float f; uint32_t u; } pv; pv.f = EXP2F(t);
                    unsigned short pt = (unsigned short)(pv.u >> 16);
                    Lsum[g] += bf2f(pt);
                    Pp[g][st][r] = (short)pt;
                }
            }
        }
        // PV: O += P·V. 32 MFMAs K=16.
        #pragma unroll
        for (int nb = 0; nb < 8; ++nb) {
            #pragma unroll
            for (int g = 0; g < 2; ++g) {
                oacc[g][nb] = MFMA16BF(Pp[g][0], vf[0][nb], oacc[g][nb]);
                oacc[g][nb] = MFMA16BF(Pp[g][1], vf[1][nb], oacc[g][nb]);
            }
        }
    }

    // Lsum: lane holds partial for m = lo; reduce over the 4 quad replicas.
    #pragma unroll
    for (int g = 0; g < 2; ++g) {
        float xr = Lsum[g];
        xr += __shfl_xor(xr, 16, 64);
        xr += __shfl_xor(xr, 32, 64);
        Lsum[g] = xr;
    }
    #pragma unroll
    for (int g = 0; g < 2; ++g) {
        #pragma unroll
        for (int nb = 0; nb < 8; ++nb) {
            #pragma unroll
            for (int r = 0; r < 4; ++r) {
                int m = b * 4096 + qbase + g * 16 + quad * 4 + r;
                part[((size_t)z * 16384 + m) * 128 + nb * 16 + lo] = f2bf(oacc[g][nb][r]);
            }
        }
        if (lane < 16) {
            int m = b * 4096 + qbase + g * 16 + lane;
            lpart[(size_t)z * 16384 + m] = Lsum[g];
        }
    }
}

// ---------------------------------------------------------------------------
// Kernel 3: combine partials; y = (o @ Wo) * gamma (unchanged).
// ---------------------------------------------------------------------------
__global__ __launch_bounds__(256) void outproj_kernel(
    const unsigned short* __restrict__ part,
    const float* __restrict__ lpart,
    const unsigned short* __restrict__ wot,
    const float* __restrict__ gamma,
    float* __restrict__ out,
    int nsplit)
{
    const int rowtile = blockIdx.x;
    const int tid  = threadIdx.x;
    const int lane = tid & 63, wave = tid >> 6;
    const int lo   = lane & 15, quad = lane >> 4;

    __shared__ __align__(16) unsigned short Os[64][136];
    __shared__ __align__(16) unsigned short WoT[128][136];

    #pragma unroll
    for (int i = 0; i < 4; ++i) {
        int flat = (i * 256 + tid) * 8;
        int row = flat >> 7, col = flat & 127;
        int m = rowtile * 64 + row;
        float acc8[8] = {0.f,0.f,0.f,0.f,0.f,0.f,0.f,0.f};
        float l = 0.f;
        for (int zz = 0; zz < nsplit; ++zz) {
            short8 t = *(const short8*)(part + ((size_t)zz * 16384 + m) * 128 + col);
            #pragma unroll
            for (int j = 0; j < 8; ++j) acc8[j] += bf2f((unsigned short)t[j]);
            l += lpart[(size_t)zz * 16384 + m];
        }
        float inv = 1.0f / l;
        short8 o8;
        #pragma unroll
        for (int j = 0; j < 8; ++j) o8[j] = (short)f2bf(acc8[j] * inv);
        *(short8*)(&Os[row][col]) = o8;
    }

    const int wc = tid >> 1, wa0 = (tid & 1) * 64;
    for (int ch = 0; ch < 2; ++ch) {
        if (ch) __syncthreads();
        #pragma unroll
        for (int j = 0; j < 8; ++j)
            *(short8*)(&WoT[wc][wa0 + j * 8]) =
                *(const short8*)(wot + (size_t)(ch * 128 + wc) * 128 + wa0 + j * 8);
        __syncthreads();

        f32x4 acc[8];
        #pragma unroll
        for (int i = 0; i < 8; ++i) acc[i] = (f32x4){0.f, 0.f, 0.f, 0.f};
        #pragma unroll
        for (int ks = 0; ks < 4; ++ks) {
            bf16x8 a = *(const bf16x8*)(&Os[wave * 16 + lo][ks * 32 + quad * 8]);
            #pragma unroll
            for (int nb = 0; nb < 8; ++nb) {
                bf16x8 bf = *(const bf16x8*)(&WoT[nb * 16 + lo][ks * 32 + quad * 8]);
                acc[nb] = MFMA32BF(a, bf, acc[nb]);
            }
        }
        #pragma unroll
        for (int nb = 0; nb < 8; ++nb) {
            int c = ch * 128 + nb * 16 + lo;
            float g = gamma[c];
            #pragma unroll
            for (int r = 0; r < 4; ++r) {
                int m = rowtile * 64 + wave * 16 + quad * 4 + r;
                out[(size_t)m * 256 + c] = acc[nb][r] * g;
            }
        }
    }
}

// ---------------------------------------------------------------------------
extern "C" void kernel_launch(void* const* d_in, const int* in_sizes, int n_in,
                              void* d_out, int out_size, void* d_ws, size_t ws_size,
                              hipStream_t stream) {
    const float* x  = (const float*)d_in[0];
    const float* Wq = (const float*)d_in[1];
    const float* Wk = (const float*)d_in[2];
    const float* Wv = (const float*)d_in[3];
    const float* Wo = (const float*)d_in[4];
    const float* wg = (const float*)d_in[5];
    float* out = (float*)d_out;

    unsigned short* ws = (unsigned short*)d_ws;
    const int nsplit = (ws_size >= (size_t)47000000) ? 8 : 4;
    const int chunk  = 4096 / nsplit;

    unsigned short* qkv_ws = ws;
    unsigned short* part   = ws + (size_t)3 * 2097152u;
    unsigned short* wt_hi  = part;
    unsigned short* wt_lo  = part + 98304u;
    float* lpart = (float*)(part + (size_t)nsplit * 2097152u);
    unsigned short* wot = (unsigned short*)(lpart + (size_t)nsplit * 16384u);
    float* gamma = (float*)(wot + 32768u);

    prep_kernel<<<dim3(17), 256, 0, stream>>>(Wq, Wk, Wv, Wo, wg, wt_hi, wt_lo, wot, gamma);
    qkv_kernel<<<dim3(256, 3), 256, 0, stream>>>(x, wt_hi, wt_lo, qkv_ws);
    attn_kernel<<<dim3(4, 32, nsplit), 256, 0, stream>>>(qkv_ws, part, lpart, chunk);
    outproj_kernel<<<dim3(256), 256, 0, stream>>>(part, lpart, wot, gamma, out, nsplit);
}

// Round 13
// 180.325 us; speedup vs baseline: 1.2103x; 1.2103x over previous
//
#include <hip/hip_runtime.h>
#include <hip/hip_bf16.h>
#include <cstdint>
#include <cstddef>

typedef __bf16 bf16x8 __attribute__((ext_vector_type(8)));
typedef _Float16 f16x8 __attribute__((ext_vector_type(8)));
typedef short short8 __attribute__((ext_vector_type(8)));
typedef short short4v __attribute__((ext_vector_type(4)));
typedef float f32x4 __attribute__((ext_vector_type(4)));

// Device pass: gfx950 MFMA builtins (HW-verified rounds 8-10). Host pass:
// inert stand-ins (host only parses device bodies, never executes them).
#if defined(__HIP_DEVICE_COMPILE__)
  #define MFMA16BF(a,b,c)  __builtin_amdgcn_mfma_f32_16x16x16bf16_1k((a),(b),(c),0,0,0)
  #define MFMA32F16(a,b,c) __builtin_amdgcn_mfma_f32_16x16x32_f16((a),(b),(c),0,0,0)
  #define MFMA32BF(a,b,c)  __builtin_amdgcn_mfma_f32_16x16x32_bf16((a),(b),(c),0,0,0)
#else
  #define MFMA16BF(a,b,c)  (c)
  #define MFMA32F16(a,b,c) (c)
  #define MFMA32BF(a,b,c)  (c)
#endif

#if defined(__HIP_DEVICE_COMPILE__) && __has_builtin(__builtin_amdgcn_exp2f)
  #define EXP2F(x) __builtin_amdgcn_exp2f(x)
#else
  #define EXP2F(x) exp2f(x)
#endif

// Barrier draining only LDS ops; leaves this wave's global prefetch in flight.
__device__ __forceinline__ void barrier_lds_only() {
    asm volatile("s_waitcnt lgkmcnt(0)\n\ts_barrier" ::: "memory");
}

__device__ __forceinline__ unsigned short f2bf(float f) {
    union { float f; uint32_t u; } v; v.f = f;
    uint32_t u = v.u;
    return (unsigned short)((u + 0x7FFFu + ((u >> 16) & 1u)) >> 16);
}
__device__ __forceinline__ float bf2f(unsigned short h) {
    union { uint32_t u; float f; } v; v.u = ((uint32_t)h) << 16;
    return v.f;
}
__device__ __forceinline__ unsigned short f2h(float f) {
    union { _Float16 h; unsigned short u; } v; v.h = (_Float16)f;
    return v.u;
}

// ---------------------------------------------------------------------------
// Kernel 1: q/k/v = leaky_relu(x @ W).  Inline hi/lo conversion of x and W
// (proven rounds 3-5).  q,k: 3-term fp32-accurate -> fp16 row-major.
// v -> bf16 transposed vt[b][d][4096].  grid (256, 3), block 256.
// ---------------------------------------------------------------------------
__global__ __launch_bounds__(256) void qkv_kernel(
    const float* __restrict__ x,
    const float* __restrict__ Wq,
    const float* __restrict__ Wk,
    const float* __restrict__ Wv,
    unsigned short* __restrict__ qkv_ws)
{
    const int rowtile = blockIdx.x;
    const int proj    = blockIdx.y;
    const float* W = (proj == 0) ? Wq : ((proj == 1) ? Wk : Wv);
    unsigned short* outqk = qkv_ws + (size_t)proj * 2097152u;
    unsigned short* vt    = qkv_ws + (size_t)2 * 2097152u;
    const bool need_lo = (proj < 2);

    const int tid  = threadIdx.x;
    const int lane = tid & 63, wave = tid >> 6;
    const int lo   = lane & 15, quad = lane >> 4;

    __shared__ __align__(16) unsigned short Xh[64][72], Xl[64][72];
    __shared__ __align__(16) unsigned short Wh[128][72], Wl[128][72];

    f32x4 acc[8];
    #pragma unroll
    for (int i = 0; i < 8; ++i) acc[i] = (f32x4){0.f, 0.f, 0.f, 0.f};

    for (int kc = 0; kc < 4; ++kc) {          // K = 256 in chunks of 64
        __syncthreads();
        #pragma unroll
        for (int i = 0; i < 4; ++i) {
            int flat4 = (i * 256 + tid) * 4;
            int row = flat4 >> 6, col = flat4 & 63;
            float4 tv4 = *(const float4*)(x + (size_t)(rowtile * 64 + row) * 256 + kc * 64 + col);
            float tv[4] = {tv4.x, tv4.y, tv4.z, tv4.w};
            short4v h, l;
            #pragma unroll
            for (int j = 0; j < 4; ++j) {
                unsigned short hj = f2bf(tv[j]);
                h[j] = (short)hj;
                l[j] = (short)f2bf(tv[j] - bf2f(hj));
            }
            *(short4v*)(&Xh[row][col]) = h;
            if (need_lo) *(short4v*)(&Xl[row][col]) = l;
        }
        {
            int n = tid & 127;
            for (int g = (tid >> 7); g < 16; g += 2) {
                int k0 = g * 4;
                short4v h, l;
                #pragma unroll
                for (int j = 0; j < 4; ++j) {
                    float wv = W[(size_t)(kc * 64 + k0 + j) * 128 + n];
                    unsigned short hj = f2bf(wv);
                    h[j] = (short)hj;
                    l[j] = (short)f2bf(wv - bf2f(hj));
                }
                *(short4v*)(&Wh[n][k0]) = h;
                if (need_lo) *(short4v*)(&Wl[n][k0]) = l;
            }
        }
        __syncthreads();
        #pragma unroll
        for (int ks = 0; ks < 2; ++ks) {
            bf16x8 ah = *(const bf16x8*)(&Xh[wave * 16 + lo][ks * 32 + quad * 8]);
            #pragma unroll
            for (int nb = 0; nb < 8; ++nb) {
                bf16x8 bh = *(const bf16x8*)(&Wh[nb * 16 + lo][ks * 32 + quad * 8]);
                acc[nb] = MFMA32BF(ah, bh, acc[nb]);
                if (need_lo) {
                    bf16x8 al = *(const bf16x8*)(&Xl[wave * 16 + lo][ks * 32 + quad * 8]);
                    bf16x8 bl = *(const bf16x8*)(&Wl[nb * 16 + lo][ks * 32 + quad * 8]);
                    acc[nb] = MFMA32BF(al, bh, acc[nb]);
                    acc[nb] = MFMA32BF(ah, bl, acc[nb]);
                }
            }
        }
    }
    if (proj < 2) {
        #pragma unroll
        for (int nb = 0; nb < 8; ++nb) {
            #pragma unroll
            for (int r = 0; r < 4; ++r) {
                float v = acc[nb][r];
                v = (v >= 0.f) ? v : 0.2f * v;
                int m = rowtile * 64 + wave * 16 + quad * 4 + r;
                outqk[(size_t)m * 128 + nb * 16 + lo] = f2h(v);
            }
        }
    } else {
        const int b  = rowtile >> 6;
        const int sb = (rowtile & 63) * 64;
        #pragma unroll
        for (int nb = 0; nb < 8; ++nb) {
            #pragma unroll
            for (int r = 0; r < 4; ++r) {
                float v = acc[nb][r];
                v = (v >= 0.f) ? v : 0.2f * v;
                int seq = sb + wave * 16 + quad * 4 + r;
                int d   = nb * 16 + lo;
                vt[(size_t)b * 524288 + (size_t)d * 4096 + seq] = f2bf(v);
            }
        }
    }
}

// ---------------------------------------------------------------------------
// Kernel 2: flash attention — round-10 configuration verbatim (best measured:
// 57.4 µs).  Software-pipelined one-deep, double-buffered K/V LDS, register-P
// (S^T C-layout == 16x16x16 A-layout), lgkmcnt-only barriers.
// grid (4, 32, nsplit), block 256.
// ---------------------------------------------------------------------------
__global__ __launch_bounds__(256) void attn_kernel(
    const unsigned short* __restrict__ qkv_ws,
    unsigned short* __restrict__ part,   // [nsplit][16384][128] bf16
    float* __restrict__ lpart,           // [nsplit][16384] fp32
    int chunk)
{
    const int b  = blockIdx.x;
    const int qt = blockIdx.y;
    const int z  = blockIdx.z;
    const int tid  = threadIdx.x;
    const int lane = tid & 63, wave = tid >> 6;
    const int lo   = lane & 15, quad = lane >> 4;

    const unsigned short* q  = qkv_ws;
    const unsigned short* k  = qkv_ws + 2097152u;
    const unsigned short* vt = qkv_ws + (size_t)2 * 2097152u + (size_t)b * 524288u;

    __shared__ __align__(16) unsigned short Ks[2][32][136];  // K fp16 [s][d]
    __shared__ __align__(16) unsigned short Vt[2][128][40];  // V^T bf16 quad-interleaved

    const int qbase = qt * 128 + wave * 32;
    f16x8 qf[2][4];
    #pragma unroll
    for (int g = 0; g < 2; ++g)
        #pragma unroll
        for (int ks = 0; ks < 4; ++ks)
            qf[g][ks] = *(const f16x8*)(q + ((size_t)(b * 4096 + qbase + g * 16 + lo)) * 128
                                          + ks * 32 + quad * 8);

    f32x4 oacc[2][8];
    #pragma unroll
    for (int g = 0; g < 2; ++g)
        #pragma unroll
        for (int i = 0; i < 8; ++i) oacc[g][i] = (f32x4){0.f, 0.f, 0.f, 0.f};
    float Lsum[2] = {1e-30f, 1e-30f};

    const float LOG2E  = 1.44269504088896f;
    const float NSHIFT = -40.0f * 1.44269504088896f;

    const int krow0 = tid >> 4, kcol0 = (tid & 15) * 8;
    const int krow1 = 16 + (tid >> 4);
    const int vd = tid >> 2, vc = tid & 3;
    const int vst  = vc >> 1;
    const int colA = ((2 * vc) & 3) * 8 + vst * 4;
    const int colB = ((2 * vc + 1) & 3) * 8 + vst * 4;

    const int niter = chunk >> 5;
    const int sbase = z * chunk;

    short8 ka, kb, va, vb;
    ka = *(const short8*)(k + ((size_t)(b * 4096 + sbase + krow0)) * 128 + kcol0);
    kb = *(const short8*)(k + ((size_t)(b * 4096 + sbase + krow1)) * 128 + kcol0);
    va = *(const short8*)(vt + (size_t)vd * 4096 + sbase + vc * 8);
    vb = *(const short8*)(vt + (size_t)(vd + 64) * 4096 + sbase + vc * 8);
    *(short8*)(&Ks[0][krow0][kcol0]) = ka;
    *(short8*)(&Ks[0][krow1][kcol0]) = kb;
    {
        short4v a0 = {va[0], va[1], va[2], va[3]}, a1 = {va[4], va[5], va[6], va[7]};
        short4v b0 = {vb[0], vb[1], vb[2], vb[3]}, b1 = {vb[4], vb[5], vb[6], vb[7]};
        *(short4v*)(&Vt[0][vd][colA])      = a0;
        *(short4v*)(&Vt[0][vd][colB])      = a1;
        *(short4v*)(&Vt[0][vd + 64][colA]) = b0;
        *(short4v*)(&Vt[0][vd + 64][colB]) = b1;
    }
    if (1 < niter) {
        const int s1 = sbase + 32;
        ka = *(const short8*)(k + ((size_t)(b * 4096 + s1 + krow0)) * 128 + kcol0);
        kb = *(const short8*)(k + ((size_t)(b * 4096 + s1 + krow1)) * 128 + kcol0);
        va = *(const short8*)(vt + (size_t)vd * 4096 + s1 + vc * 8);
        vb = *(const short8*)(vt + (size_t)(vd + 64) * 4096 + s1 + vc * 8);
    }
    barrier_lds_only();

    short4v Pp[2][2];   // P(t-1), A-frag layout (k = quad*4 + j)

    for (int kt = 0; kt < niter; ++kt) {
        const int cur = kt & 1, oth = cur ^ 1;

        // 1. QK(t): S^T = K·Q^T. 16 MFMAs K=32.
        f32x4 sT[2][2];
        sT[0][0] = (f32x4){0.f,0.f,0.f,0.f}; sT[0][1] = (f32x4){0.f,0.f,0.f,0.f};
        sT[1][0] = (f32x4){0.f,0.f,0.f,0.f}; sT[1][1] = (f32x4){0.f,0.f,0.f,0.f};
        #pragma unroll
        for (int ks = 0; ks < 4; ++ks) {
            #pragma unroll
            for (int st = 0; st < 2; ++st) {
                f16x8 kf = *(const f16x8*)(&Ks[cur][st * 16 + lo][ks * 32 + quad * 8]);
                sT[0][st] = MFMA32F16(kf, qf[0][ks], sT[0][st]);
                sT[1][st] = MFMA32F16(kf, qf[1][ks], sT[1][st]);
            }
        }
        // 2. PV(t-1): fills the MFMA pipe while QK(t) drains.
        if (kt > 0) {
            #pragma unroll
            for (int nb = 0; nb < 8; ++nb) {
                short8 vv = *(const short8*)(&Vt[oth][nb * 16 + lo][quad * 8]);
                short4v v0 = {vv[0], vv[1], vv[2], vv[3]};
                short4v v1 = {vv[4], vv[5], vv[6], vv[7]};
                #pragma unroll
                for (int g = 0; g < 2; ++g) {
                    oacc[g][nb] = MFMA16BF(Pp[g][0], v0, oacc[g][nb]);
                    oacc[g][nb] = MFMA16BF(Pp[g][1], v1, oacc[g][nb]);
                }
            }
        }
        // 3. waves done reading buf[oth]
        barrier_lds_only();
        // 4. stage tile t+1 into buf[oth]
        if (kt + 1 < niter) {
            *(short8*)(&Ks[oth][krow0][kcol0]) = ka;
            *(short8*)(&Ks[oth][krow1][kcol0]) = kb;
            short4v a0 = {va[0], va[1], va[2], va[3]}, a1 = {va[4], va[5], va[6], va[7]};
            short4v b0 = {vb[0], vb[1], vb[2], vb[3]}, b1 = {vb[4], vb[5], vb[6], vb[7]};
            *(short4v*)(&Vt[oth][vd][colA])      = a0;
            *(short4v*)(&Vt[oth][vd][colB])      = a1;
            *(short4v*)(&Vt[oth][vd + 64][colA]) = b0;
            *(short4v*)(&Vt[oth][vd + 64][colB]) = b1;
        }
        // 5. prefetch tile t+2
        if (kt + 2 < niter) {
            const int s2 = sbase + (kt + 2) * 32;
            ka = *(const short8*)(k + ((size_t)(b * 4096 + s2 + krow0)) * 128 + kcol0);
            kb = *(const short8*)(k + ((size_t)(b * 4096 + s2 + krow1)) * 128 + kcol0);
            va = *(const short8*)(vt + (size_t)vd * 4096 + s2 + vc * 8);
            vb = *(const short8*)(vt + (size_t)(vd + 64) * 4096 + s2 + vc * 8);
        }
        // 6. exp(t) on VALU
        #pragma unroll
        for (int g = 0; g < 2; ++g) {
            #pragma unroll
            for (int st = 0; st < 2; ++st) {
                #pragma unroll
                for (int r = 0; r < 4; ++r) {
                    float t = fminf(fmaf(sT[g][st][r], LOG2E, NSHIFT), 125.0f);
                    union { float f; uint32_t u; } pv; pv.f = EXP2F(t);
                    unsigned short pt = (unsigned short)(pv.u >> 16);
                    Lsum[g] += bf2f(pt);
                    Pp[g][st][r] = (short)pt;
                }
            }
        }
        // 7. stage-writes visible before next iter's QK reads
        barrier_lds_only();
    }
    // final PV(niter-1)
    {
        const int last = (niter - 1) & 1;
        #pragma unroll
        for (int nb = 0; nb < 8; ++nb) {
            short8 vv = *(const short8*)(&Vt[last][nb * 16 + lo][quad * 8]);
            short4v v0 = {vv[0], vv[1], vv[2], vv[3]};
            short4v v1 = {vv[4], vv[5], vv[6], vv[7]};
            #pragma unroll
            for (int g = 0; g < 2; ++g) {
                oacc[g][nb] = MFMA16BF(Pp[g][0], v0, oacc[g][nb]);
                oacc[g][nb] = MFMA16BF(Pp[g][1], v1, oacc[g][nb]);
            }
        }
    }

    #pragma unroll
    for (int g = 0; g < 2; ++g) {
        float xr = Lsum[g];
        xr += __shfl_xor(xr, 16, 64);
        xr += __shfl_xor(xr, 32, 64);
        Lsum[g] = xr;
    }
    #pragma unroll
    for (int g = 0; g < 2; ++g) {
        #pragma unroll
        for (int nb = 0; nb < 8; ++nb) {
            #pragma unroll
            for (int r = 0; r < 4; ++r) {
                int m = b * 4096 + qbase + g * 16 + quad * 4 + r;
                part[((size_t)z * 16384 + m) * 128 + nb * 16 + lo] = f2bf(oacc[g][nb][r]);
            }
        }
        if (lane < 16) {
            int m = b * 4096 + qbase + g * 16 + lane;
            lpart[(size_t)z * 16384 + m] = Lsum[g];
        }
    }
}

// ---------------------------------------------------------------------------
// Kernel 3: combine partials; y = (o @ Wo) * tanh(relu(1+γ)).
// 512 row-tiles of 32 rows (2 blocks/CU): part read ONCE, 2x parallelism vs
// the 256-block version.  Wo staged inline (bf16), gamma inline (1 tanhf/thr).
// grid 512, block 256.
// ---------------------------------------------------------------------------
__global__ __launch_bounds__(256) void outproj_kernel(
    const unsigned short* __restrict__ part,
    const float* __restrict__ lpart,
    const float* __restrict__ Wo,
    const float* __restrict__ wg,
    float* __restrict__ out,
    int nsplit)
{
    const int rowtile = blockIdx.x;   // 0..511, 32 rows each
    const int tid  = threadIdx.x;
    const int lane = tid & 63, wave = tid >> 6;
    const int lo   = lane & 15, quad = lane >> 4;

    __shared__ __align__(16) unsigned short Os[32][136];
    __shared__ __align__(16) unsigned short WoT[128][136];  // WoT[c][a], one half
    __shared__ float gl[256];

    {   // gamma for all 256 channels (one tanhf per thread, once per block)
        float g = 1.0f + wg[tid];
        if (g < 0.f) g = 0.f;
        gl[tid] = tanhf(g);
    }
    // combine + normalize: 32 rows x 128 d  (512 short8-chunks, 2/thread)
    #pragma unroll
    for (int i = 0; i < 2; ++i) {
        int flat = (i * 256 + tid) * 8;
        int row = flat >> 7, col = flat & 127;
        int m = rowtile * 32 + row;
        float acc8[8] = {0.f,0.f,0.f,0.f,0.f,0.f,0.f,0.f};
        float l = 0.f;
        for (int zz = 0; zz < nsplit; ++zz) {
            short8 t = *(const short8*)(part + ((size_t)zz * 16384 + m) * 128 + col);
            #pragma unroll
            for (int j = 0; j < 8; ++j) acc8[j] += bf2f((unsigned short)t[j]);
            l += lpart[(size_t)zz * 16384 + m];
        }
        float inv = 1.0f / l;
        short8 o8;
        #pragma unroll
        for (int j = 0; j < 8; ++j) o8[j] = (short)f2bf(acc8[j] * inv);
        *(short8*)(&Os[row][col]) = o8;
    }

    // wave -> (row group, col sub-half): rg = wave&1 (16 rows), csub = wave>>1 (64 cols)
    const int rg = wave & 1, csub = wave >> 1;

    for (int ch = 0; ch < 2; ++ch) {
        if (ch) __syncthreads();   // all MFMA reads of WoT[ch=0] done
        // stage WoT[c][a] for this col half; reads coalesced over c
        {
            int c = tid & 127;
            for (int g = (tid >> 7); g < 16; g += 2) {
                int a0 = g * 8;
                short8 t;
                #pragma unroll
                for (int j = 0; j < 8; ++j)
                    t[j] = (short)f2bf(Wo[(size_t)(a0 + j) * 256 + ch * 128 + c]);
                *(short8*)(&WoT[c][a0]) = t;
            }
        }
        __syncthreads();

        f32x4 acc[4];
        #pragma unroll
        for (int i = 0; i < 4; ++i) acc[i] = (f32x4){0.f, 0.f, 0.f, 0.f};
        #pragma unroll
        for (int ks = 0; ks < 4; ++ks) {
            bf16x8 a = *(const bf16x8*)(&Os[rg * 16 + lo][ks * 32 + quad * 8]);
            #pragma unroll
            for (int nb = 0; nb < 4; ++nb) {
                bf16x8 bf = *(const bf16x8*)(&WoT[csub * 64 + nb * 16 + lo][ks * 32 + quad * 8]);
                acc[nb] = MFMA32BF(a, bf, acc[nb]);
            }
        }
        #pragma unroll
        for (int nb = 0; nb < 4; ++nb) {
            int c = ch * 128 + csub * 64 + nb * 16 + lo;
            float g = gl[c];
            #pragma unroll
            for (int r = 0; r < 4; ++r) {
                int m = rowtile * 32 + rg * 16 + quad * 4 + r;
                out[(size_t)m * 256 + c] = acc[nb][r] * g;
            }
        }
    }
}

// ---------------------------------------------------------------------------
extern "C" void kernel_launch(void* const* d_in, const int* in_sizes, int n_in,
                              void* d_out, int out_size, void* d_ws, size_t ws_size,
                              hipStream_t stream) {
    const float* x  = (const float*)d_in[0];
    const float* Wq = (const float*)d_in[1];
    const float* Wk = (const float*)d_in[2];
    const float* Wv = (const float*)d_in[3];
    const float* Wo = (const float*)d_in[4];
    const float* wg = (const float*)d_in[5];
    float* out = (float*)d_out;

    unsigned short* ws = (unsigned short*)d_ws;
    const int nsplit = (ws_size >= (size_t)47000000) ? 8 : 4;
    const int chunk  = 4096 / nsplit;

    // layout (2B units): q@0, k@2Mi, vt@4Mi | part nsplit*2Mi | lpart
    unsigned short* qkv_ws = ws;
    unsigned short* part   = ws + (size_t)3 * 2097152u;
    float* lpart = (float*)(part + (size_t)nsplit * 2097152u);

    qkv_kernel<<<dim3(256, 3), 256, 0, stream>>>(x, Wq, Wk, Wv, qkv_ws);
    attn_kernel<<<dim3(4, 32, nsplit), 256, 0, stream>>>(qkv_ws, part, lpart, chunk);
    outproj_kernel<<<dim3(512), 256, 0, stream>>>(part, lpart, Wo, wg, out, nsplit);
}

// Round 14
// 175.709 us; speedup vs baseline: 1.2421x; 1.0263x over previous
//
#include <hip/hip_runtime.h>
#include <hip/hip_bf16.h>
#include <cstdint>
#include <cstddef>

typedef __bf16 bf16x8 __attribute__((ext_vector_type(8)));
typedef _Float16 f16x8 __attribute__((ext_vector_type(8)));
typedef short short8 __attribute__((ext_vector_type(8)));
typedef short short4v __attribute__((ext_vector_type(4)));
typedef float f32x4 __attribute__((ext_vector_type(4)));

#if defined(__HIP_DEVICE_COMPILE__)
  #define MFMA16BF(a,b,c)  __builtin_amdgcn_mfma_f32_16x16x16bf16_1k((a),(b),(c),0,0,0)
  #define MFMA32F16(a,b,c) __builtin_amdgcn_mfma_f32_16x16x32_f16((a),(b),(c),0,0,0)
  #define MFMA32BF(a,b,c)  __builtin_amdgcn_mfma_f32_16x16x32_bf16((a),(b),(c),0,0,0)
#else
  #define MFMA16BF(a,b,c)  (c)
  #define MFMA32F16(a,b,c) (c)
  #define MFMA32BF(a,b,c)  (c)
#endif

#if defined(__HIP_DEVICE_COMPILE__) && __has_builtin(__builtin_amdgcn_exp2f)
  #define EXP2F(x) __builtin_amdgcn_exp2f(x)
#else
  #define EXP2F(x) exp2f(x)
#endif

__device__ __forceinline__ void barrier_lds_only() {
    asm volatile("s_waitcnt lgkmcnt(0)\n\ts_barrier" ::: "memory");
}

__device__ __forceinline__ unsigned short f2bf(float f) {
    union { float f; uint32_t u; } v; v.f = f;
    uint32_t u = v.u;
    return (unsigned short)((u + 0x7FFFu + ((u >> 16) & 1u)) >> 16);
}
__device__ __forceinline__ float bf2f(unsigned short h) {
    union { uint32_t u; float f; } v; v.u = ((uint32_t)h) << 16;
    return v.f;
}
__device__ __forceinline__ unsigned short f2h(float f) {
    union { _Float16 h; unsigned short u; } v; v.h = (_Float16)f;
    return v.u;
}

// ---------------------------------------------------------------------------
// Kernel 0: preconvert.
// bid 0..11 (proj,kc): W -> MFMA B-fragment layout, bf16 hi (+lo for q,k):
//   wfh[((proj*4+kc)*16 + ks*8 + nb)*512 + lane*8 + j]
//     = bf16( W[kc*64 + ks*32 + (lane>>4)*8 + j][nb*16 + (lane&15)] )
// bid 12..15: Wo -> wot[256c][128a] bf16.   bid 16: gamma = tanh(relu(1+wg)).
// ---------------------------------------------------------------------------
__global__ __launch_bounds__(256) void prep_kernel(
    const float* __restrict__ Wq, const float* __restrict__ Wk,
    const float* __restrict__ Wv, const float* __restrict__ Wo,
    const float* __restrict__ wg,
    unsigned short* __restrict__ wfh,
    unsigned short* __restrict__ wfl,
    unsigned short* __restrict__ wot,
    float* __restrict__ gamma)
{
    const int bid = blockIdx.x, t = threadIdx.x;
    __shared__ __align__(16) unsigned short Tsc[64][136];
    if (bid < 12) {
        const int proj = bid >> 2, kc = bid & 3;
        const float* W = (proj == 0) ? Wq : ((proj == 1) ? Wk : Wv);
        #pragma unroll
        for (int s = 0; s < 4; ++s) {
            int idx = s * 256 + t;            // 0..1023
            int frag = idx >> 6, lane = idx & 63;
            int ks = frag >> 3, nb = frag & 7;
            int lo = lane & 15, quad = lane >> 4;
            short8 h8, l8;
            #pragma unroll
            for (int j = 0; j < 8; ++j) {
                float w = W[(size_t)(kc * 64 + ks * 32 + quad * 8 + j) * 128 + nb * 16 + lo];
                unsigned short hi = f2bf(w);
                h8[j] = (short)hi;
                l8[j] = (short)f2bf(w - bf2f(hi));
            }
            size_t base = ((size_t)(proj * 4 + kc) * 16 + frag) * 512 + lane * 8;
            *(short8*)(wfh + base) = h8;
            if (proj < 2)
                *(short8*)(wfl + base) = l8;
        }
    } else if (bid < 16) {
        const int c0 = (bid - 12) * 64;
        for (int r = 0; r < 32; ++r) {
            int idx = r * 256 + t;
            int a = idx >> 6, cc = idx & 63;
            Tsc[cc][a] = f2bf(Wo[(size_t)a * 256 + c0 + cc]);
        }
        __syncthreads();
        int cc = t >> 2, a0 = (t & 3) * 32;
        #pragma unroll
        for (int j = 0; j < 4; ++j)
            *(short8*)(wot + (size_t)(c0 + cc) * 128 + a0 + j * 8) =
                *(const short8*)(&Tsc[cc][a0 + j * 8]);
    } else {
        float g = 1.0f + wg[t];
        if (g < 0.f) g = 0.f;
        gamma[t] = tanhf(g);
    }
}

// ---------------------------------------------------------------------------
// Kernel 1: FUSED q/k/v = leaky_relu(x @ W).  One block does all 3 proj for a
// 64-row tile: x staged+converted ONCE (double-buffered, register prefetch,
// lgkmcnt-only barriers).  W B-frags loaded DIRECT from the preconverted
// fragment-layout global (one coalesced 1KB b128 per frag, L1-hot).
// q,k: 3-term fp32-accurate -> fp16 row-major; v -> bf16 vt[b][d][4096].
// grid 256, block 256.
// ---------------------------------------------------------------------------
__global__ __launch_bounds__(256) void qkv_kernel(
    const float* __restrict__ x,
    const unsigned short* __restrict__ wfh,
    const unsigned short* __restrict__ wfl,
    unsigned short* __restrict__ qkv_ws)
{
    const int rowtile = blockIdx.x;
    const int tid  = threadIdx.x;
    const int lane = tid & 63, wave = tid >> 6;
    const int lo   = lane & 15, quad = lane >> 4;

    __shared__ __align__(16) unsigned short Xh[2][64][72], Xl[2][64][72];

    f32x4 acc[3][8];
    #pragma unroll
    for (int p = 0; p < 3; ++p)
        #pragma unroll
        for (int i = 0; i < 8; ++i) acc[p][i] = (f32x4){0.f, 0.f, 0.f, 0.f};

    // x map: 4 float4/thread: row = flat4>>6, col = flat4&63
    int xrow[4], xcol[4];
    #pragma unroll
    for (int i = 0; i < 4; ++i) {
        int flat4 = (i * 256 + tid) * 4;
        xrow[i] = flat4 >> 6;
        xcol[i] = flat4 & 63;
    }
    const float* xb = x + (size_t)rowtile * 64 * 256;

    // stage chunk 0
    #pragma unroll
    for (int i = 0; i < 4; ++i) {
        float4 tv4 = *(const float4*)(xb + (size_t)xrow[i] * 256 + 0 * 64 + xcol[i]);
        float tv[4] = {tv4.x, tv4.y, tv4.z, tv4.w};
        short4v h, l;
        #pragma unroll
        for (int j = 0; j < 4; ++j) {
            unsigned short hj = f2bf(tv[j]);
            h[j] = (short)hj;
            l[j] = (short)f2bf(tv[j] - bf2f(hj));
        }
        *(short4v*)(&Xh[0][xrow[i]][xcol[i]]) = h;
        *(short4v*)(&Xl[0][xrow[i]][xcol[i]]) = l;
    }
    // prefetch chunk 1
    float4 xr[4];
    #pragma unroll
    for (int i = 0; i < 4; ++i)
        xr[i] = *(const float4*)(xb + (size_t)xrow[i] * 256 + 1 * 64 + xcol[i]);
    barrier_lds_only();

    for (int kc = 0; kc < 4; ++kc) {
        const int cur = kc & 1, oth = cur ^ 1;
        // compute: 3 projections on Xh/Xl[cur]; W frags direct from global
        #pragma unroll
        for (int proj = 0; proj < 3; ++proj) {
            const unsigned short* wh = wfh + ((size_t)(proj * 4 + kc) * 16) * 512 + lane * 8;
            const unsigned short* wl = wfl + ((size_t)(proj * 4 + kc) * 16) * 512 + lane * 8;
            #pragma unroll
            for (int ks = 0; ks < 2; ++ks) {
                bf16x8 ah = *(const bf16x8*)(&Xh[cur][wave * 16 + lo][ks * 32 + quad * 8]);
                bf16x8 al = *(const bf16x8*)(&Xl[cur][wave * 16 + lo][ks * 32 + quad * 8]);
                #pragma unroll
                for (int nb = 0; nb < 8; ++nb) {
                    bf16x8 bh = *(const bf16x8*)(wh + (size_t)(ks * 8 + nb) * 512);
                    acc[proj][nb] = MFMA32BF(ah, bh, acc[proj][nb]);
                    if (proj < 2) {
                        bf16x8 bl = *(const bf16x8*)(wl + (size_t)(ks * 8 + nb) * 512);
                        acc[proj][nb] = MFMA32BF(al, bh, acc[proj][nb]);
                        acc[proj][nb] = MFMA32BF(ah, bl, acc[proj][nb]);
                    }
                }
            }
        }
        barrier_lds_only();           // all waves done reading buf[cur]
        if (kc + 1 < 4) {             // convert+write prefetched chunk into buf[oth]
            #pragma unroll
            for (int i = 0; i < 4; ++i) {
                float tv[4] = {xr[i].x, xr[i].y, xr[i].z, xr[i].w};
                short4v h, l;
                #pragma unroll
                for (int j = 0; j < 4; ++j) {
                    unsigned short hj = f2bf(tv[j]);
                    h[j] = (short)hj;
                    l[j] = (short)f2bf(tv[j] - bf2f(hj));
                }
                *(short4v*)(&Xh[oth][xrow[i]][xcol[i]]) = h;
                *(short4v*)(&Xl[oth][xrow[i]][xcol[i]]) = l;
            }
        }
        if (kc + 2 < 4) {             // prefetch chunk kc+2
            #pragma unroll
            for (int i = 0; i < 4; ++i)
                xr[i] = *(const float4*)(xb + (size_t)xrow[i] * 256 + (kc + 2) * 64 + xcol[i]);
        }
        barrier_lds_only();           // stage-writes visible
    }

    // epilogues
    #pragma unroll
    for (int p = 0; p < 2; ++p) {
        unsigned short* outqk = qkv_ws + (size_t)p * 2097152u;
        #pragma unroll
        for (int nb = 0; nb < 8; ++nb) {
            #pragma unroll
            for (int r = 0; r < 4; ++r) {
                float v = acc[p][nb][r];
                v = (v >= 0.f) ? v : 0.2f * v;
                int m = rowtile * 64 + wave * 16 + quad * 4 + r;
                outqk[(size_t)m * 128 + nb * 16 + lo] = f2h(v);
            }
        }
    }
    {
        unsigned short* vt = qkv_ws + (size_t)2 * 2097152u;
        const int b  = rowtile >> 6;
        const int sb = (rowtile & 63) * 64;
        #pragma unroll
        for (int nb = 0; nb < 8; ++nb) {
            #pragma unroll
            for (int r = 0; r < 4; ++r) {
                float v = acc[2][nb][r];
                v = (v >= 0.f) ? v : 0.2f * v;
                int seq = sb + wave * 16 + quad * 4 + r;
                int d   = nb * 16 + lo;
                vt[(size_t)b * 524288 + (size_t)d * 4096 + seq] = f2bf(v);
            }
        }
    }
}

// ---------------------------------------------------------------------------
// Kernel 2: flash attention — round-10 configuration verbatim (57.4-57.9 µs,
// best measured).  grid (4, 32, nsplit), block 256.
// ---------------------------------------------------------------------------
__global__ __launch_bounds__(256) void attn_kernel(
    const unsigned short* __restrict__ qkv_ws,
    unsigned short* __restrict__ part,
    float* __restrict__ lpart,
    int chunk)
{
    const int b  = blockIdx.x;
    const int qt = blockIdx.y;
    const int z  = blockIdx.z;
    const int tid  = threadIdx.x;
    const int lane = tid & 63, wave = tid >> 6;
    const int lo   = lane & 15, quad = lane >> 4;

    const unsigned short* q  = qkv_ws;
    const unsigned short* k  = qkv_ws + 2097152u;
    const unsigned short* vt = qkv_ws + (size_t)2 * 2097152u + (size_t)b * 524288u;

    __shared__ __align__(16) unsigned short Ks[2][32][136];
    __shared__ __align__(16) unsigned short Vt[2][128][40];

    const int qbase = qt * 128 + wave * 32;
    f16x8 qf[2][4];
    #pragma unroll
    for (int g = 0; g < 2; ++g)
        #pragma unroll
        for (int ks = 0; ks < 4; ++ks)
            qf[g][ks] = *(const f16x8*)(q + ((size_t)(b * 4096 + qbase + g * 16 + lo)) * 128
                                          + ks * 32 + quad * 8);

    f32x4 oacc[2][8];
    #pragma unroll
    for (int g = 0; g < 2; ++g)
        #pragma unroll
        for (int i = 0; i < 8; ++i) oacc[g][i] = (f32x4){0.f, 0.f, 0.f, 0.f};
    float Lsum[2] = {1e-30f, 1e-30f};

    const float LOG2E  = 1.44269504088896f;
    const float NSHIFT = -40.0f * 1.44269504088896f;

    const int krow0 = tid >> 4, kcol0 = (tid & 15) * 8;
    const int krow1 = 16 + (tid >> 4);
    const int vd = tid >> 2, vc = tid & 3;
    const int vst  = vc >> 1;
    const int colA = ((2 * vc) & 3) * 8 + vst * 4;
    const int colB = ((2 * vc + 1) & 3) * 8 + vst * 4;

    const int niter = chunk >> 5;
    const int sbase = z * chunk;

    short8 ka, kb, va, vb;
    ka = *(const short8*)(k + ((size_t)(b * 4096 + sbase + krow0)) * 128 + kcol0);
    kb = *(const short8*)(k + ((size_t)(b * 4096 + sbase + krow1)) * 128 + kcol0);
    va = *(const short8*)(vt + (size_t)vd * 4096 + sbase + vc * 8);
    vb = *(const short8*)(vt + (size_t)(vd + 64) * 4096 + sbase + vc * 8);
    *(short8*)(&Ks[0][krow0][kcol0]) = ka;
    *(short8*)(&Ks[0][krow1][kcol0]) = kb;
    {
        short4v a0 = {va[0], va[1], va[2], va[3]}, a1 = {va[4], va[5], va[6], va[7]};
        short4v b0 = {vb[0], vb[1], vb[2], vb[3]}, b1 = {vb[4], vb[5], vb[6], vb[7]};
        *(short4v*)(&Vt[0][vd][colA])      = a0;
        *(short4v*)(&Vt[0][vd][colB])      = a1;
        *(short4v*)(&Vt[0][vd + 64][colA]) = b0;
        *(short4v*)(&Vt[0][vd + 64][colB]) = b1;
    }
    if (1 < niter) {
        const int s1 = sbase + 32;
        ka = *(const short8*)(k + ((size_t)(b * 4096 + s1 + krow0)) * 128 + kcol0);
        kb = *(const short8*)(k + ((size_t)(b * 4096 + s1 + krow1)) * 128 + kcol0);
        va = *(const short8*)(vt + (size_t)vd * 4096 + s1 + vc * 8);
        vb = *(const short8*)(vt + (size_t)(vd + 64) * 4096 + s1 + vc * 8);
    }
    barrier_lds_only();

    short4v Pp[2][2];

    for (int kt = 0; kt < niter; ++kt) {
        const int cur = kt & 1, oth = cur ^ 1;

        f32x4 sT[2][2];
        sT[0][0] = (f32x4){0.f,0.f,0.f,0.f}; sT[0][1] = (f32x4){0.f,0.f,0.f,0.f};
        sT[1][0] = (f32x4){0.f,0.f,0.f,0.f}; sT[1][1] = (f32x4){0.f,0.f,0.f,0.f};
        #pragma unroll
        for (int ks = 0; ks < 4; ++ks) {
            #pragma unroll
            for (int st = 0; st < 2; ++st) {
                f16x8 kf = *(const f16x8*)(&Ks[cur][st * 16 + lo][ks * 32 + quad * 8]);
                sT[0][st] = MFMA32F16(kf, qf[0][ks], sT[0][st]);
                sT[1][st] = MFMA32F16(kf, qf[1][ks], sT[1][st]);
            }
        }
        if (kt > 0) {
            #pragma unroll
            for (int nb = 0; nb < 8; ++nb) {
                short8 vv = *(const short8*)(&Vt[oth][nb * 16 + lo][quad * 8]);
                short4v v0 = {vv[0], vv[1], vv[2], vv[3]};
                short4v v1 = {vv[4], vv[5], vv[6], vv[7]};
                #pragma unroll
                for (int g = 0; g < 2; ++g) {
                    oacc[g][nb] = MFMA16BF(Pp[g][0], v0, oacc[g][nb]);
                    oacc[g][nb] = MFMA16BF(Pp[g][1], v1, oacc[g][nb]);
                }
            }
        }
        barrier_lds_only();
        if (kt + 1 < niter) {
            *(short8*)(&Ks[oth][krow0][kcol0]) = ka;
            *(short8*)(&Ks[oth][krow1][kcol0]) = kb;
            short4v a0 = {va[0], va[1], va[2], va[3]}, a1 = {va[4], va[5], va[6], va[7]};
            short4v b0 = {vb[0], vb[1], vb[2], vb[3]}, b1 = {vb[4], vb[5], vb[6], vb[7]};
            *(short4v*)(&Vt[oth][vd][colA])      = a0;
            *(short4v*)(&Vt[oth][vd][colB])      = a1;
            *(short4v*)(&Vt[oth][vd + 64][colA]) = b0;
            *(short4v*)(&Vt[oth][vd + 64][colB]) = b1;
        }
        if (kt + 2 < niter) {
            const int s2 = sbase + (kt + 2) * 32;
            ka = *(const short8*)(k + ((size_t)(b * 4096 + s2 + krow0)) * 128 + kcol0);
            kb = *(const short8*)(k + ((size_t)(b * 4096 + s2 + krow1)) * 128 + kcol0);
            va = *(const short8*)(vt + (size_t)vd * 4096 + s2 + vc * 8);
            vb = *(const short8*)(vt + (size_t)(vd + 64) * 4096 + s2 + vc * 8);
        }
        #pragma unroll
        for (int g = 0; g < 2; ++g) {
            #pragma unroll
            for (int st = 0; st < 2; ++st) {
                #pragma unroll
                for (int r = 0; r < 4; ++r) {
                    float t = fminf(fmaf(sT[g][st][r], LOG2E, NSHIFT), 125.0f);
                    union { float f; uint32_t u; } pv; pv.f = EXP2F(t);
                    unsigned short pt = (unsigned short)(pv.u >> 16);
                    Lsum[g] += bf2f(pt);
                    Pp[g][st][r] = (short)pt;
                }
            }
        }
        barrier_lds_only();
    }
    {
        const int last = (niter - 1) & 1;
        #pragma unroll
        for (int nb = 0; nb < 8; ++nb) {
            short8 vv = *(const short8*)(&Vt[last][nb * 16 + lo][quad * 8]);
            short4v v0 = {vv[0], vv[1], vv[2], vv[3]};
            short4v v1 = {vv[4], vv[5], vv[6], vv[7]};
            #pragma unroll
            for (int g = 0; g < 2; ++g) {
                oacc[g][nb] = MFMA16BF(Pp[g][0], v0, oacc[g][nb]);
                oacc[g][nb] = MFMA16BF(Pp[g][1], v1, oacc[g][nb]);
            }
        }
    }

    #pragma unroll
    for (int g = 0; g < 2; ++g) {
        float xr = Lsum[g];
        xr += __shfl_xor(xr, 16, 64);
        xr += __shfl_xor(xr, 32, 64);
        Lsum[g] = xr;
    }
    #pragma unroll
    for (int g = 0; g < 2; ++g) {
        #pragma unroll
        for (int nb = 0; nb < 8; ++nb) {
            #pragma unroll
            for (int r = 0; r < 4; ++r) {
                int m = b * 4096 + qbase + g * 16 + quad * 4 + r;
                part[((size_t)z * 16384 + m) * 128 + nb * 16 + lo] = f2bf(oacc[g][nb][r]);
            }
        }
        if (lane < 16) {
            int m = b * 4096 + qbase + g * 16 + lane;
            lpart[(size_t)z * 16384 + m] = Lsum[g];
        }
    }
}

// ---------------------------------------------------------------------------
// Kernel 3: combine partials; y = (o @ Wo) * gamma.  512 row-tiles of 32 rows
// (2 blocks/CU, part read once); WoT and gamma preconverted.
// grid 512, block 256.
// ---------------------------------------------------------------------------
__global__ __launch_bounds__(256) void outproj_kernel(
    const unsigned short* __restrict__ part,
    const float* __restrict__ lpart,
    const unsigned short* __restrict__ wot,
    const float* __restrict__ gamma,
    float* __restrict__ out,
    int nsplit)
{
    const int rowtile = blockIdx.x;   // 0..511, 32 rows each
    const int tid  = threadIdx.x;
    const int lane = tid & 63, wave = tid >> 6;
    const int lo   = lane & 15, quad = lane >> 4;

    __shared__ __align__(16) unsigned short Os[32][136];
    __shared__ __align__(16) unsigned short WoT[128][136];

    #pragma unroll
    for (int i = 0; i < 2; ++i) {
        int flat = (i * 256 + tid) * 8;
        int row = flat >> 7, col = flat & 127;
        int m = rowtile * 32 + row;
        float acc8[8] = {0.f,0.f,0.f,0.f,0.f,0.f,0.f,0.f};
        float l = 0.f;
        for (int zz = 0; zz < nsplit; ++zz) {
            short8 t = *(const short8*)(part + ((size_t)zz * 16384 + m) * 128 + col);
            #pragma unroll
            for (int j = 0; j < 8; ++j) acc8[j] += bf2f((unsigned short)t[j]);
            l += lpart[(size_t)zz * 16384 + m];
        }
        float inv = 1.0f / l;
        short8 o8;
        #pragma unroll
        for (int j = 0; j < 8; ++j) o8[j] = (short)f2bf(acc8[j] * inv);
        *(short8*)(&Os[row][col]) = o8;
    }

    const int rg = wave & 1, csub = wave >> 1;
    const int wc = tid >> 1, wa0 = (tid & 1) * 64;

    for (int ch = 0; ch < 2; ++ch) {
        if (ch) __syncthreads();
        #pragma unroll
        for (int j = 0; j < 8; ++j)
            *(short8*)(&WoT[wc][wa0 + j * 8]) =
                *(const short8*)(wot + (size_t)(ch * 128 + wc) * 128 + wa0 + j * 8);
        __syncthreads();

        f32x4 acc[4];
        #pragma unroll
        for (int i = 0; i < 4; ++i) acc[i] = (f32x4){0.f, 0.f, 0.f, 0.f};
        #pragma unroll
        for (int ks = 0; ks < 4; ++ks) {
            bf16x8 a = *(const bf16x8*)(&Os[rg * 16 + lo][ks * 32 + quad * 8]);
            #pragma unroll
            for (int nb = 0; nb < 4; ++nb) {
                bf16x8 bf = *(const bf16x8*)(&WoT[csub * 64 + nb * 16 + lo][ks * 32 + quad * 8]);
                acc[nb] = MFMA32BF(a, bf, acc[nb]);
            }
        }
        #pragma unroll
        for (int nb = 0; nb < 4; ++nb) {
            int c = ch * 128 + csub * 64 + nb * 16 + lo;
            float g = gamma[c];
            #pragma unroll
            for (int r = 0; r < 4; ++r) {
                int m = rowtile * 32 + rg * 16 + quad * 4 + r;
                out[(size_t)m * 256 + c] = acc[nb][r] * g;
            }
        }
    }
}

// ---------------------------------------------------------------------------
extern "C" void kernel_launch(void* const* d_in, const int* in_sizes, int n_in,
                              void* d_out, int out_size, void* d_ws, size_t ws_size,
                              hipStream_t stream) {
    const float* x  = (const float*)d_in[0];
    const float* Wq = (const float*)d_in[1];
    const float* Wk = (const float*)d_in[2];
    const float* Wv = (const float*)d_in[3];
    const float* Wo = (const float*)d_in[4];
    const float* wg = (const float*)d_in[5];
    float* out = (float*)d_out;

    unsigned short* ws = (unsigned short*)d_ws;
    const int nsplit = (ws_size >= (size_t)47000000) ? 8 : 4;
    const int chunk  = 4096 / nsplit;

    // layout (2B units): qkv_ws 3*2Mi | part nsplit*2Mi | lpart | wot | gamma
    // wfh/wfl overlay at part start (consumed by qkv before attn writes part)
    unsigned short* qkv_ws = ws;
    unsigned short* part   = ws + (size_t)3 * 2097152u;
    unsigned short* wfh    = part;                 // 98304 shorts
    unsigned short* wfl    = part + 98304u;        // 65536 shorts
    float* lpart = (float*)(part + (size_t)nsplit * 2097152u);
    unsigned short* wot = (unsigned short*)(lpart + (size_t)nsplit * 16384u);
    float* gamma = (float*)(wot + 32768u);

    prep_kernel<<<dim3(17), 256, 0, stream>>>(Wq, Wk, Wv, Wo, wg, wfh, wfl, wot, gamma);
    qkv_kernel<<<dim3(256), 256, 0, stream>>>(x, wfh, wfl, qkv_ws);
    attn_kernel<<<dim3(4, 32, nsplit), 256, 0, stream>>>(qkv_ws, part, lpart, chunk);
    outproj_kernel<<<dim3(512), 256, 0, stream>>>(part, lpart, wot, gamma, out, nsplit);
}